// Round 1
// baseline (142.415 us; speedup 1.0000x reference)
//
#include <hip/hip_runtime.h>

// STDP learner: per-row decayed trace scan + scatter-add into vocab + clip.
// B=1024 rows, S=8192 steps, VOCAB=128000.

#define VOCAB_N 128000
#define B_ROWS  1024
#define S_LEN   8192

// exp(-1/5)
constexpr float TRACE_DECAY = 0.8187307530779818586699355f;
// exp(-32/5) = TRACE_DECAY^32
constexpr float A32 = 1.6615572731739319903e-3f;
constexpr float LR_PLUS = 0.01f;
constexpr float W_DECAY = 0.99f;

// One block per row; 256 threads x 32 contiguous timesteps each.
__global__ __launch_bounds__(256) void stdp_scan_scatter(
    const int* __restrict__ token_ids,
    const float* __restrict__ spikes,
    float* __restrict__ grad)
{
    const int row  = blockIdx.x;
    const int tid  = threadIdx.x;
    const int lane = tid & 63;
    const int wid  = tid >> 6;
    const long base = (long)row * S_LEN + (long)tid * 32;

    // Load 32 spikes into registers (8x float4, coalesced-enough; full lines used).
    float s[32];
    const float4* sp4 = reinterpret_cast<const float4*>(spikes + base);
    #pragma unroll
    for (int c = 0; c < 8; ++c) {
        float4 v = sp4[c];
        s[c * 4 + 0] = v.x; s[c * 4 + 1] = v.y;
        s[c * 4 + 2] = v.z; s[c * 4 + 3] = v.w;
    }

    // Local affine reduction over the 32-chunk: state_out = A32*state_in + L,
    // L = sum_j s_j * d^(31-j).
    float L = 0.f;
    #pragma unroll
    for (int j = 0; j < 32; ++j) L = fmaf(L, TRACE_DECAY, s[j]);

    // Inclusive pair-scan of affine functions across the wave (Kogge-Stone).
    // (A,B): state -> A*state + B.   combine(prev, cur) = (Ac*Ap, Ac*Bp + Bc)
    float A = A32, Bv = L;
    #pragma unroll
    for (int o = 1; o < 64; o <<= 1) {
        float Ao = __shfl_up(A, o);
        float Bo = __shfl_up(Bv, o);
        if (lane >= o) { Bv = fmaf(A, Bo, Bv); A = A * Ao; }
    }

    // Cross-wave fixup (4 waves).
    __shared__ float wA[4], wB[4];
    if (lane == 63) { wA[wid] = A; wB[wid] = Bv; }
    __syncthreads();
    float carry = 0.f;
    #pragma unroll
    for (int w = 0; w < 3; ++w)
        if (w < wid) carry = fmaf(wA[w], carry, wB[w]);

    // Exclusive scan value = incoming trace state for this thread's chunk.
    float Ae = __shfl_up(A, 1), Be = __shfl_up(Bv, 1);
    if (lane == 0) { Ae = 1.f; Be = 0.f; }
    float trace = fmaf(Ae, carry, Be);

    // Pass 2: replay recurrence exactly, scatter nonzero updates.
    const int4* tk4 = reinterpret_cast<const int4*>(token_ids + base);
    #pragma unroll
    for (int c = 0; c < 8; ++c) {
        int4 t = tk4[c];
        int tt[4] = {t.x, t.y, t.z, t.w};
        #pragma unroll
        for (int j = 0; j < 4; ++j) {
            float sv = s[c * 4 + j];
            trace = fmaf(trace, TRACE_DECAY, sv);
            if (sv != 0.f) {
                atomicAdd(&grad[tt[j]], LR_PLUS * trace);
            }
        }
    }
}

// out[v] = clip((w[v] + grad[v]) * 0.99, 0, 1); grad accumulated in-place in out.
__global__ __launch_bounds__(256) void stdp_finalize(
    const float* __restrict__ token_weights,
    float* __restrict__ out, int n)
{
    int v = blockIdx.x * 256 + threadIdx.x;
    if (v < n) {
        float g = out[v];
        float w = (token_weights[v] + g) * W_DECAY;
        out[v] = fminf(fmaxf(w, 0.f), 1.f);
    }
}

extern "C" void kernel_launch(void* const* d_in, const int* in_sizes, int n_in,
                              void* d_out, int out_size, void* d_ws, size_t ws_size,
                              hipStream_t stream) {
    const int*   token_ids = (const int*)d_in[0];
    const float* spikes    = (const float*)d_in[1];
    const float* tw        = (const float*)d_in[2];
    float* out = (float*)d_out;

    // d_out is NOT re-zeroed between timed replays -> zero it ourselves.
    hipMemsetAsync(out, 0, (size_t)out_size * sizeof(float), stream);

    stdp_scan_scatter<<<B_ROWS, 256, 0, stream>>>(token_ids, spikes, out);

    int nblk = (out_size + 255) / 256;
    stdp_finalize<<<nblk, 256, 0, stream>>>(tw, out, out_size);
}

// Round 2
// 139.411 us; speedup vs baseline: 1.0215x; 1.0215x over previous
//
#include <hip/hip_runtime.h>

// STDP learner: per-row decayed trace scan + scatter-add into vocab + clip.
// B=1024 rows, S=8192 steps, VOCAB=128000.

#define VOCAB_N 128000
#define B_ROWS  1024
#define S_LEN   8192

// exp(-1/5)
constexpr float TRACE_DECAY = 0.8187307530779818586699355f;
// exp(-16/5) = TRACE_DECAY^16
constexpr float A16 = 0.040762203978366211696f;
constexpr float LR_PLUS = 0.01f;
constexpr float W_DECAY = 0.99f;

// One block (512 threads = 8 waves) per row; 16 contiguous timesteps/thread.
// All global loads happen BEFORE any atomic so the in-order vmcnt never
// forces draining fire-and-forget atomics.
__global__ __launch_bounds__(512) void stdp_scan_scatter(
    const int* __restrict__ token_ids,
    const float* __restrict__ spikes,
    float* __restrict__ grad)
{
    const int row  = blockIdx.x;
    const int tid  = threadIdx.x;
    const int lane = tid & 63;
    const int wid  = tid >> 6;   // 0..7
    const long base = (long)row * S_LEN + (long)tid * 16;

    // ---- Load everything first: 16 spikes (4x float4) + 16 tokens (4x int4).
    float s[16];
    int   tok[16];
    {
        const float4* sp4 = reinterpret_cast<const float4*>(spikes + base);
        const int4*   tk4 = reinterpret_cast<const int4*>(token_ids + base);
        float4 a0 = sp4[0], a1 = sp4[1], a2 = sp4[2], a3 = sp4[3];
        int4   b0 = tk4[0], b1 = tk4[1], b2 = tk4[2], b3 = tk4[3];
        s[0]=a0.x; s[1]=a0.y; s[2]=a0.z; s[3]=a0.w;
        s[4]=a1.x; s[5]=a1.y; s[6]=a1.z; s[7]=a1.w;
        s[8]=a2.x; s[9]=a2.y; s[10]=a2.z; s[11]=a2.w;
        s[12]=a3.x; s[13]=a3.y; s[14]=a3.z; s[15]=a3.w;
        tok[0]=b0.x; tok[1]=b0.y; tok[2]=b0.z; tok[3]=b0.w;
        tok[4]=b1.x; tok[5]=b1.y; tok[6]=b1.z; tok[7]=b1.w;
        tok[8]=b2.x; tok[9]=b2.y; tok[10]=b2.z; tok[11]=b2.w;
        tok[12]=b3.x; tok[13]=b3.y; tok[14]=b3.z; tok[15]=b3.w;
    }

    // ---- Local affine reduction: state_out = A16*state_in + L.
    float L = 0.f;
    #pragma unroll
    for (int j = 0; j < 16; ++j) L = fmaf(L, TRACE_DECAY, s[j]);

    // ---- Inclusive Kogge-Stone pair-scan of affine functions across 64 lanes.
    float A = A16, Bv = L;
    #pragma unroll
    for (int o = 1; o < 64; o <<= 1) {
        float Ao = __shfl_up(A, o);
        float Bo = __shfl_up(Bv, o);
        if (lane >= o) { Bv = fmaf(A, Bo, Bv); A = A * Ao; }
    }

    // ---- Cross-wave fixup (8 waves).
    __shared__ float wA[8], wB[8];
    if (lane == 63) { wA[wid] = A; wB[wid] = Bv; }
    __syncthreads();
    float carry = 0.f;
    #pragma unroll
    for (int w = 0; w < 7; ++w)
        if (w < wid) carry = fmaf(wA[w], carry, wB[w]);

    // ---- Exclusive scan value = incoming trace state for this thread's chunk.
    float Ae = __shfl_up(A, 1), Be = __shfl_up(Bv, 1);
    if (lane == 0) { Ae = 1.f; Be = 0.f; }
    float trace = fmaf(Ae, carry, Be);

    // ---- Replay recurrence; scatter nonzero updates (pure atomic tail).
    #pragma unroll
    for (int j = 0; j < 16; ++j) {
        trace = fmaf(trace, TRACE_DECAY, s[j]);
        if (s[j] != 0.f) {
            atomicAdd(&grad[tok[j]], LR_PLUS * trace);
        }
    }
}

// out[v] = clip((w[v] + grad[v]) * 0.99, 0, 1); grad accumulated in-place in out.
__global__ __launch_bounds__(256) void stdp_finalize(
    const float* __restrict__ token_weights,
    float* __restrict__ out, int n)
{
    int v = blockIdx.x * 256 + threadIdx.x;
    if (v < n) {
        float g = out[v];
        float w = (token_weights[v] + g) * W_DECAY;
        out[v] = fminf(fmaxf(w, 0.f), 1.f);
    }
}

extern "C" void kernel_launch(void* const* d_in, const int* in_sizes, int n_in,
                              void* d_out, int out_size, void* d_ws, size_t ws_size,
                              hipStream_t stream) {
    const int*   token_ids = (const int*)d_in[0];
    const float* spikes    = (const float*)d_in[1];
    const float* tw        = (const float*)d_in[2];
    float* out = (float*)d_out;

    // d_out is NOT re-zeroed between timed replays -> zero it ourselves.
    hipMemsetAsync(out, 0, (size_t)out_size * sizeof(float), stream);

    stdp_scan_scatter<<<B_ROWS, 512, 0, stream>>>(token_ids, spikes, out);

    int nblk = (out_size + 255) / 256;
    stdp_finalize<<<nblk, 256, 0, stream>>>(tw, out, out_size);
}

// Round 3
// 59.772 us; speedup vs baseline: 2.3826x; 2.3324x over previous
//
#include <hip/hip_runtime.h>

// STDP learner: per-row decayed trace scan + scatter-add into vocab + clip.
// B=1024 rows, S=8192 steps, VOCAB=128000.
//
// Strategy: global scattered atomicAdd throughput (~19/ns measured) was the
// bound. Replace with: (1) scan + pack nonzero updates (tok|bf16) into 8
// vocab-range buckets, (2) per-range LDS histograms -> dense partials,
// (3) reduce partials + clip. Global atomics: 8 per block (cursors only).

#define VOCAB_N 128000
#define B_ROWS  1024
#define S_LEN   8192
#define NRANGE  8
#define VR      16000          // vocab bins per range (62.5 KB LDS histogram)
#define G2      32             // partial-histogram blocks per range

constexpr float TRACE_DECAY = 0.8187307530779818586699355f;  // exp(-1/5)
constexpr float A16 = 0.040762203978366211696f;              // TRACE_DECAY^16
constexpr float LR_PLUS = 0.01f;
constexpr float W_DECAY = 0.99f;

// ---------------- Kernel 1: scan + pack + bucket-partition ----------------
// One block (512 threads = 8 waves) per row; 16 contiguous timesteps/thread.
__global__ __launch_bounds__(512) void stdp_scan_bucket(
    const int* __restrict__ token_ids,
    const float* __restrict__ spikes,
    unsigned* __restrict__ cursors,   // [NRANGE]
    unsigned* __restrict__ pairs,     // [NRANGE][cap]
    unsigned cap)
{
    const int row  = blockIdx.x;
    const int tid  = threadIdx.x;
    const int lane = tid & 63;
    const int wid  = tid >> 6;   // 0..7
    const long base = (long)row * S_LEN + (long)tid * 16;

    float s[16];
    int   tok[16];
    {
        const float4* sp4 = reinterpret_cast<const float4*>(spikes + base);
        const int4*   tk4 = reinterpret_cast<const int4*>(token_ids + base);
        float4 a0 = sp4[0], a1 = sp4[1], a2 = sp4[2], a3 = sp4[3];
        int4   b0 = tk4[0], b1 = tk4[1], b2 = tk4[2], b3 = tk4[3];
        s[0]=a0.x; s[1]=a0.y; s[2]=a0.z; s[3]=a0.w;
        s[4]=a1.x; s[5]=a1.y; s[6]=a1.z; s[7]=a1.w;
        s[8]=a2.x; s[9]=a2.y; s[10]=a2.z; s[11]=a2.w;
        s[12]=a3.x; s[13]=a3.y; s[14]=a3.z; s[15]=a3.w;
        tok[0]=b0.x; tok[1]=b0.y; tok[2]=b0.z; tok[3]=b0.w;
        tok[4]=b1.x; tok[5]=b1.y; tok[6]=b1.z; tok[7]=b1.w;
        tok[8]=b2.x; tok[9]=b2.y; tok[10]=b2.z; tok[11]=b2.w;
        tok[12]=b3.x; tok[13]=b3.y; tok[14]=b3.z; tok[15]=b3.w;
    }

    // ---- Affine-function scan (verified in rounds 1-2). Local reduction:
    float L = 0.f;
    #pragma unroll
    for (int j = 0; j < 16; ++j) L = fmaf(L, TRACE_DECAY, s[j]);

    // Inclusive Kogge-Stone pair-scan across 64 lanes.
    float A = A16, Bv = L;
    #pragma unroll
    for (int o = 1; o < 64; o <<= 1) {
        float Ao = __shfl_up(A, o);
        float Bo = __shfl_up(Bv, o);
        if (lane >= o) { Bv = fmaf(A, Bo, Bv); A = A * Ao; }
    }

    // Cross-wave fixup.
    __shared__ float wAf[8], wBf[8];
    if (lane == 63) { wAf[wid] = A; wBf[wid] = Bv; }
    __syncthreads();
    float carry = 0.f;
    #pragma unroll
    for (int w = 0; w < 7; ++w)
        if (w < wid) carry = fmaf(wAf[w], carry, wBf[w]);

    float Ae = __shfl_up(A, 1), Be = __shfl_up(Bv, 1);
    if (lane == 0) { Ae = 1.f; Be = 0.f; }
    const float t0 = fmaf(Ae, carry, Be);   // incoming trace for this chunk

    // ---- Pass A: count nonzero updates per vocab range.
    // Counts packed in a u64 (8 x 8-bit fields) to avoid runtime-indexed
    // register arrays (-> scratch).
    unsigned long long cnt64 = 0ull;
    {
        float tr = t0;
        #pragma unroll
        for (int j = 0; j < 16; ++j) {
            tr = fmaf(tr, TRACE_DECAY, s[j]);
            if (s[j] != 0.f) {
                int r = tok[j] / VR;          // magic-mul div by 16000
                cnt64 += 1ull << (r << 3);
            }
        }
    }

    // ---- Per-range exclusive rank: wave shfl-scan + cross-wave LDS scan.
    __shared__ int      wsum[8][NRANGE];
    __shared__ unsigned bbase[NRANGE];
    unsigned long long offlo = 0ull, offhi = 0ull;  // 16-bit fields: excl rank
    #pragma unroll
    for (int r = 0; r < NRANGE; ++r) {
        int v = (int)((cnt64 >> (r * 8)) & 0xFF);
        int inc = v;
        #pragma unroll
        for (int o = 1; o < 64; o <<= 1) {
            int u = __shfl_up(inc, o);
            if (lane >= o) inc += u;
        }
        int excl = inc - v;
        int tot  = __shfl(inc, 63);
        if (lane == 0) wsum[wid][r] = tot;
        if (r < 4) offlo |= (unsigned long long)(unsigned)excl << (16 * r);
        else       offhi |= (unsigned long long)(unsigned)excl << (16 * (r - 4));
    }
    __syncthreads();

    if (tid < NRANGE) {
        unsigned tot = 0;
        #pragma unroll
        for (int w = 0; w < 8; ++w) tot += (unsigned)wsum[w][tid];
        bbase[tid] = atomicAdd(&cursors[tid], tot);   // 8 atomics per block
    }
    __syncthreads();

    // Add cross-wave base into the packed per-range offsets.
    #pragma unroll
    for (int r = 0; r < NRANGE; ++r) {
        int wb = 0;
        #pragma unroll
        for (int w = 0; w < 7; ++w)
            if (w < wid) wb += wsum[w][r];
        if (r < 4) offlo += (unsigned long long)(unsigned)wb << (16 * r);
        else       offhi += (unsigned long long)(unsigned)wb << (16 * (r - 4));
    }

    // ---- Pass B: replay recurrence, pack (bf16 update | 17-bit token), write.
    {
        float tr = t0;
        #pragma unroll
        for (int j = 0; j < 16; ++j) {
            tr = fmaf(tr, TRACE_DECAY, s[j]);
            if (s[j] != 0.f) {
                float upd = LR_PLUS * tr;                   // in (0, 0.054]
                unsigned b = __float_as_uint(upd);
                b += 0x7FFFu + ((b >> 16) & 1u);            // RTNE to bf16
                unsigned pk = ((b >> 16) << 17) | (unsigned)tok[j];
                int r = tok[j] / VR;
                unsigned slot;
                if (r < 4) {
                    int sh = r << 4;
                    slot = (unsigned)((offlo >> sh) & 0xFFFFull);
                    offlo += 1ull << sh;
                } else {
                    int sh = (r - 4) << 4;
                    slot = (unsigned)((offhi >> sh) & 0xFFFFull);
                    offhi += 1ull << sh;
                }
                unsigned gs = bbase[r] + slot;
                if (gs < cap) pairs[(size_t)r * cap + gs] = pk;
            }
        }
    }
}

// ---------------- Kernel 2: per-range LDS histogram -> dense partials ------
__global__ __launch_bounds__(256) void stdp_bin(
    const unsigned* __restrict__ cursors,
    const unsigned* __restrict__ pairs,
    float* __restrict__ part,   // [NRANGE][G2][VR]
    unsigned cap)
{
    __shared__ float bins[VR];                 // 62.5 KB
    const int r = blockIdx.x / G2;
    const int g = blockIdx.x - r * G2;

    for (int i = threadIdx.x; i < VR; i += 256) bins[i] = 0.f;
    __syncthreads();

    unsigned count = cursors[r];
    if (count > cap) count = cap;
    unsigned chunk = (count + G2 - 1) / G2;
    unsigned lo = (unsigned)g * chunk;
    unsigned hi = lo + chunk; if (hi > count) hi = count;

    const unsigned* bp = pairs + (size_t)r * cap;
    const int rbase = r * VR;
    for (unsigned i = lo + threadIdx.x; i < hi; i += 256) {
        unsigned p = bp[i];
        int t = (int)(p & 0x1FFFFu) - rbase;
        float v = __uint_as_float((p >> 17) << 16);
        atomicAdd(&bins[t], v);                // LDS atomic (ds_add_f32)
    }
    __syncthreads();

    float* o = part + ((size_t)(r * G2 + g)) * VR;
    for (int i = threadIdx.x; i < VR; i += 256) o[i] = bins[i];
}

// ---------------- Kernel 3: reduce partials + clip -------------------------
__global__ __launch_bounds__(256) void stdp_reduce(
    const float* __restrict__ token_weights,
    const float* __restrict__ part,
    float* __restrict__ out, int n)
{
    int v = blockIdx.x * 256 + threadIdx.x;
    if (v >= n) return;
    int r = v / VR;
    int l = v - r * VR;
    const float* p = part + (size_t)r * G2 * VR + l;
    float acc = 0.f;
    #pragma unroll
    for (int g = 0; g < G2; ++g) acc += p[(size_t)g * VR];
    float w = (token_weights[v] + acc) * W_DECAY;
    out[v] = fminf(fmaxf(w, 0.f), 1.f);
}

// ---------------- Fallback path (round-2, correct but 139 us) --------------
constexpr float TRACE_DECAY_F = 0.8187307530779818586699355f;

__global__ __launch_bounds__(512) void stdp_scan_scatter(
    const int* __restrict__ token_ids,
    const float* __restrict__ spikes,
    float* __restrict__ grad)
{
    const int row  = blockIdx.x;
    const int tid  = threadIdx.x;
    const int lane = tid & 63;
    const int wid  = tid >> 6;
    const long base = (long)row * S_LEN + (long)tid * 16;

    float s[16]; int tok[16];
    {
        const float4* sp4 = reinterpret_cast<const float4*>(spikes + base);
        const int4*   tk4 = reinterpret_cast<const int4*>(token_ids + base);
        float4 a0 = sp4[0], a1 = sp4[1], a2 = sp4[2], a3 = sp4[3];
        int4   b0 = tk4[0], b1 = tk4[1], b2 = tk4[2], b3 = tk4[3];
        s[0]=a0.x; s[1]=a0.y; s[2]=a0.z; s[3]=a0.w;
        s[4]=a1.x; s[5]=a1.y; s[6]=a1.z; s[7]=a1.w;
        s[8]=a2.x; s[9]=a2.y; s[10]=a2.z; s[11]=a2.w;
        s[12]=a3.x; s[13]=a3.y; s[14]=a3.z; s[15]=a3.w;
        tok[0]=b0.x; tok[1]=b0.y; tok[2]=b0.z; tok[3]=b0.w;
        tok[4]=b1.x; tok[5]=b1.y; tok[6]=b1.z; tok[7]=b1.w;
        tok[8]=b2.x; tok[9]=b2.y; tok[10]=b2.z; tok[11]=b2.w;
        tok[12]=b3.x; tok[13]=b3.y; tok[14]=b3.z; tok[15]=b3.w;
    }

    float L = 0.f;
    #pragma unroll
    for (int j = 0; j < 16; ++j) L = fmaf(L, TRACE_DECAY_F, s[j]);
    float A = A16, Bv = L;
    #pragma unroll
    for (int o = 1; o < 64; o <<= 1) {
        float Ao = __shfl_up(A, o);
        float Bo = __shfl_up(Bv, o);
        if (lane >= o) { Bv = fmaf(A, Bo, Bv); A = A * Ao; }
    }
    __shared__ float wA[8], wB[8];
    if (lane == 63) { wA[wid] = A; wB[wid] = Bv; }
    __syncthreads();
    float carry = 0.f;
    #pragma unroll
    for (int w = 0; w < 7; ++w)
        if (w < wid) carry = fmaf(wA[w], carry, wB[w]);
    float Ae = __shfl_up(A, 1), Be = __shfl_up(Bv, 1);
    if (lane == 0) { Ae = 1.f; Be = 0.f; }
    float trace = fmaf(Ae, carry, Be);

    #pragma unroll
    for (int j = 0; j < 16; ++j) {
        trace = fmaf(trace, TRACE_DECAY_F, s[j]);
        if (s[j] != 0.f) atomicAdd(&grad[tok[j]], LR_PLUS * trace);
    }
}

__global__ __launch_bounds__(256) void stdp_finalize(
    const float* __restrict__ token_weights,
    float* __restrict__ out, int n)
{
    int v = blockIdx.x * 256 + threadIdx.x;
    if (v < n) {
        float g = out[v];
        float w = (token_weights[v] + g) * W_DECAY;
        out[v] = fminf(fmaxf(w, 0.f), 1.f);
    }
}

// ---------------- Host launcher -------------------------------------------
extern "C" void kernel_launch(void* const* d_in, const int* in_sizes, int n_in,
                              void* d_out, int out_size, void* d_ws, size_t ws_size,
                              hipStream_t stream) {
    const int*   token_ids = (const int*)d_in[0];
    const float* spikes    = (const float*)d_in[1];
    const float* tw        = (const float*)d_in[2];
    float* out = (float*)d_out;

    // Workspace layout: [16 u32 header(cursors)] [NRANGE*cap u32 pairs]
    //                   [NRANGE*G2*VR f32 partials]
    const size_t part_bytes = (size_t)NRANGE * G2 * VR * 4;
    // Expected pairs/bucket ~315K (30% spike density, uniform tokens).
    // Tiers: 1.31M covers even 100% density; 655K = 2.1x margin; 393K = 1.25x.
    unsigned cap = 0;
    const unsigned tiers[3] = {1310720u, 655360u, 393216u};
    for (int t = 0; t < 3; ++t) {
        size_t need = 64 + (size_t)NRANGE * tiers[t] * 4 + part_bytes;
        if (ws_size >= need) { cap = tiers[t]; break; }
    }

    if (cap != 0) {
        unsigned* cursors = (unsigned*)d_ws;
        unsigned* pairs   = cursors + 16;
        float*    part    = (float*)(pairs + (size_t)NRANGE * cap);

        hipMemsetAsync(cursors, 0, 64, stream);
        stdp_scan_bucket<<<B_ROWS, 512, 0, stream>>>(token_ids, spikes,
                                                     cursors, pairs, cap);
        stdp_bin<<<NRANGE * G2, 256, 0, stream>>>(cursors, pairs, part, cap);
        stdp_reduce<<<(out_size + 255) / 256, 256, 0, stream>>>(tw, part, out,
                                                                out_size);
    } else {
        // Fallback: direct global atomics.
        hipMemsetAsync(out, 0, (size_t)out_size * sizeof(float), stream);
        stdp_scan_scatter<<<B_ROWS, 512, 0, stream>>>(token_ids, spikes, out);
        stdp_finalize<<<(out_size + 255) / 256, 256, 0, stream>>>(tw, out,
                                                                  out_size);
    }
}